// Round 15
// baseline (134.950 us; speedup 1.0000x reference)
//
#include <hip/hip_runtime.h>
#include <math.h>

#define CDIM 8
#define CSZ  4096
#define NB   8
#define ND   1024
#define NT   4096
#define NFR  (NB * NT)
#define TAU  2e-5f                   // f16-split-MFMA vs f64 sim gap (worst-stack ~5e-6, 4x margin)

typedef float    f32x4  __attribute__((ext_vector_type(4)));
typedef float    f32x16 __attribute__((ext_vector_type(16)));
typedef _Float16 f16x8  __attribute__((ext_vector_type(8)));

// async global->LDS, 16B per lane; dest must be linear-in-lane (ours is)
#define GLOAD_LDS16(gp, lp) __builtin_amdgcn_global_load_lds( \
    (const __attribute__((address_space(1))) void*)(gp), \
    (__attribute__((address_space(3))) void*)(lp), 16, 0, 0)

// ---- d_out layout (flat f32, return order) ----
static constexpr size_t CL_OFF  = (size_t)NB * ND * NT;
static constexpr size_t CBL_OFF = CL_OFF + NB;
static constexpr size_t IDX_OFF = CBL_OFF + NB;
static constexpr size_t LAT_OFF = IDX_OFF + (size_t)NB * NT;

// ---- d_ws layout (byte offsets, 16B aligned) ----
static constexpr size_t WT64_B   = 0;                          // f64[16384]
static constexpr size_t CBN64A_B = 131072;                     // f64[4096*8]
static constexpr size_t CBN64B_B = 393216;                     // f64[4096*8]
static constexpr size_t CARR_B   = 655360;                     // f16x8 [book*3+plane][4096] = 384 KB
static constexpr size_t ZA64_B   = 1048576;                    // f64[NFR*16] = 4 MB
static constexpr size_t IDXW_B   = 5242880;                    // i32[NFR]
static constexpr size_t EARR_B   = 5373952;                    // f16x8 [frame][book*3+slot] = 3 MB
static constexpr size_t PART_B   = 8519680;                    // f64[512]
static constexpr size_t WS_NEED  = PART_B + 512 * 8;           // ~8.52 MB

// split x: hi (f16) + lo*64 (f16) + hi/64 (f16); |x|<2^-10 routed all-lo (no denorm loss).
// sim = chi*ehi + (chi/64)*(elo*64) + (clo*64)*(ehi/64)
__device__ __forceinline__ void split16(float x, _Float16& hi, _Float16& lo64, _Float16& hi64) {
    const _Float16 h = (fabsf(x) < 0.0009765625f) ? (_Float16)0.f : (_Float16)x;
    const float hf = (float)h;
    hi   = h;
    lo64 = (_Float16)((x - hf) * 64.f);
    hi64 = (_Float16)(hf * 0.015625f);
}

// ================= prep: wT64 + f64-normalized codebooks + f16-split planes =================
__global__ void vq_prep(const float* __restrict__ w_in_a, const float* __restrict__ w_in_b,
                        const float* __restrict__ cb_a,  const float* __restrict__ cb_b,
                        double* __restrict__ wT64,
                        double* __restrict__ cbn64A, double* __restrict__ cbn64B,
                        f16x8* __restrict__ carr) {
    int id = blockIdx.x * 256 + threadIdx.x;
    if (id < 16384) {
        int i = id >> 4, o = id & 15;
        float w = (o < 8) ? w_in_a[o * ND + i] : w_in_b[(o - 8) * ND + i];
        wT64[id] = (double)w;
    } else if (id < 16384 + 2 * CSZ) {
        int e = id - 16384;
        int book = e >> 12, j = e & (CSZ - 1);
        const float* src = (book ? cb_b : cb_a) + (size_t)j * CDIM;
        double* d64 = (book ? cbn64B : cbn64A) + (size_t)j * CDIM;
        double c[CDIM]; double n2 = 0.0;
#pragma unroll
        for (int k = 0; k < CDIM; ++k) { c[k] = (double)src[k]; n2 = fma(c[k], c[k], n2); }
        double den = fmax(sqrt(n2), 1e-12);
        f16x8 p0, p1, p2;
#pragma unroll
        for (int k = 0; k < CDIM; ++k) {
            double v = c[k] / den;
            d64[k] = v;
            _Float16 hi, lo64, hi64;
            split16((float)v, hi, lo64, hi64);
            p0[k] = hi; p1[k] = hi64; p2[k] = lo64;   // plane1 = chi/64, plane2 = clo*64
        }
        const size_t base = (size_t)(book * 3) * CSZ + j;
        carr[base]           = p0;
        carr[base + CSZ]     = p1;
        carr[base + 2 * CSZ] = p2;
    }
}

// ================= A: f64 projection (proven 512x512 shape) =================
__global__ void __launch_bounds__(512, 4)
vq_proj(const float* __restrict__ z,
        const float* __restrict__ b_in_a, const float* __restrict__ b_in_b,
        const double* __restrict__ wT64,
        double* __restrict__ za64, f16x8* __restrict__ earr,
        float* __restrict__ out) {
    const int tid  = threadIdx.x;
    const int lane = tid & 63;
    const int wave = __builtin_amdgcn_readfirstlane(tid >> 6);  // 0..7
    const int blk  = blockIdx.x;
    const int b    = blk >> 6;
    const int t    = ((blk & 63) << 6) + lane;
    const int f    = (blk << 6) + lane;

    __shared__ double red[8][64][9];                            // 36.9 KB

    double acc[16];
#pragma unroll
    for (int k = 0; k < 16; ++k) acc[k] = 0.0;

    const float* zp = z + ((size_t)b * ND) * NT + t;
    const int i0 = wave * 128;
#pragma unroll 8
    for (int ii = 0; ii < 128; ++ii) {
        const int i = i0 + ii;
        const double zd = (double)zp[(size_t)i * NT];
        const double* wr = wT64 + (size_t)i * 16;               // uniform -> s_load
#pragma unroll
        for (int k = 0; k < 16; ++k) acc[k] = fma(wr[k], zd, acc[k]);
    }

    double za16[16];
#pragma unroll
    for (int r = 0; r < 2; ++r) {
#pragma unroll
        for (int k = 0; k < 8; ++k) red[wave][lane][k] = acc[8 * r + k];
        __syncthreads();
        if (wave == 0) {
#pragma unroll
            for (int k = 0; k < 8; ++k) {
                double s = red[0][lane][k];
#pragma unroll
                for (int w = 1; w < 8; ++w) s += red[w][lane][k];
                za16[8 * r + k] = s;
            }
        }
        __syncthreads();
    }
    if (wave != 0) return;

#pragma unroll
    for (int k = 0; k < 8; ++k) { za16[k] += (double)b_in_a[k]; za16[8 + k] += (double)b_in_b[k]; }

    // latent output (f32)
#pragma unroll
    for (int k = 0; k < 16; ++k)
        out[LAT_OFF + ((size_t)b * 16 + k) * NT + t] = (float)za16[k];

    // store za64 (rescue + losses)
    double* zf = za64 + (size_t)f * 16;
#pragma unroll
    for (int k = 0; k < 16; ++k) zf[k] = za16[k];

    // normalize f64 -> f16-split slots [f][book*3 + {ehi, elo*64, ehi/64}]
    double n2a = 0.0, n2b = 0.0;
#pragma unroll
    for (int k = 0; k < 8; ++k) { n2a = fma(za16[k], za16[k], n2a); n2b = fma(za16[8+k], za16[8+k], n2b); }
    const double ia_ = 1.0 / fmax(sqrt(n2a), 1e-12);
    const double ib_ = 1.0 / fmax(sqrt(n2b), 1e-12);
#pragma unroll
    for (int book = 0; book < 2; ++book) {
        const double inv = book ? ib_ : ia_;
        f16x8 s0, s1, s2;
#pragma unroll
        for (int k = 0; k < 8; ++k) {
            const float e32 = (float)(za16[book * 8 + k] * inv);
            _Float16 hi, lo64, hi64;
            split16(e32, hi, lo64, hi64);
            s0[k] = hi; s1[k] = lo64; s2[k] = hi64;
        }
        const size_t base = (size_t)f * 6 + book * 3;
        earr[base]     = s0;
        earr[base + 1] = s1;
        earr[base + 2] = s2;
    }
}

// ================= B: MFMA scan, double-buffered staging + rescue + idx + loss =================
// 512 blocks x 256 thr; 16 chunks of 256 entries; 2 x 24 KB LDS buffers (same 48 KB total).
__global__ void __launch_bounds__(256, 2)
vq_scan32(const f16x8* __restrict__ carr, const f16x8* __restrict__ earr,
          const double* __restrict__ za64,
          const double* __restrict__ cbn64A, const double* __restrict__ cbn64B,
          const float* __restrict__ cb_a, const float* __restrict__ cb_b,
          int* __restrict__ idxAB, float* __restrict__ out, double* __restrict__ part) {
    __shared__ f16x8 lds[2][6 * 256];                           // 2 x 24 KB
    __shared__ int sE[2][64], sN[2][64], sCode[64], sList[64];
    __shared__ int sCnt;

    const int tid  = threadIdx.x;
    const int lane = tid & 63;
    const int wave = __builtin_amdgcn_readfirstlane(tid >> 6);  // 0..3
    const int book = wave & 1;
    const int fg   = wave >> 1;
    const int h    = lane >> 5;                                 // k-half
    const int c32  = lane & 31;
    const int fl   = fg * 32 + c32;
    const int bf   = blockIdx.x * 64;
    const int f    = bf + fl;

    const f16x8 s0 = earr[(size_t)f * 6 + book * 3];
    const f16x8 s1 = earr[(size_t)f * 6 + book * 3 + 1];
    const f16x8 s2 = earr[(size_t)f * 6 + book * 3 + 2];
    f16x8 fz;
#pragma unroll
    for (int j = 0; j < 8; ++j) fz[j] = (_Float16)0.f;
    const f16x8 bf1 = h ? s1 : s0;
    const f16x8 bf2 = h ? fz : s2;

    float b1 = -1e30f, b2 = -1e30f;
    int   bt = 0;

    // prologue: stage chunk 0
#pragma unroll
    for (int it = 0; it < 6; ++it) {
        const int idx = it * 256 + tid;
        GLOAD_LDS16(carr + (size_t)(idx >> 8) * CSZ + (idx & 255), &lds[0][idx]);
    }
    __syncthreads();

    for (int ch = 0; ch < 16; ++ch) {
        const int cur = ch & 1;
        if (ch + 1 < 16) {                                      // issue next chunk async
#pragma unroll
            for (int it = 0; it < 6; ++it) {
                const int idx = it * 256 + tid;
                GLOAD_LDS16(carr + (size_t)(idx >> 8) * CSZ + ((ch + 1) << 8) + (idx & 255),
                            &lds[cur ^ 1][idx]);
            }
        }
        const f16x8* pa1 = &lds[cur][(book * 3 + h) * 256];     // loads hide under MFMA
        const f16x8* pa2 = &lds[cur][(book * 3 + 2) * 256];
#pragma unroll
        for (int t = 0; t < 8; ++t) {                           // 8 tiles of 32 entries
            const f16x8 af1 = pa1[(t << 5) + c32];
            const f16x8 af2 = pa2[(t << 5) + c32];
            f32x16 zc = {};
            f32x16 acc = __builtin_amdgcn_mfma_f32_32x32x16_f16(af1, bf1, zc, 0, 0, 0);
            acc = __builtin_amdgcn_mfma_f32_32x32x16_f16(af2, bf2, acc, 0, 0, 0);
            // max3-shaped tree (max is exactly associative: identical value, fewer insts)
            const float m0 = fmaxf(fmaxf(acc[0],  acc[1]),  acc[2]);
            const float m1 = fmaxf(fmaxf(acc[3],  acc[4]),  acc[5]);
            const float m2 = fmaxf(fmaxf(acc[6],  acc[7]),  acc[8]);
            const float m3 = fmaxf(fmaxf(acc[9],  acc[10]), acc[11]);
            const float m4 = fmaxf(fmaxf(acc[12], acc[13]), acc[14]);
            const float t0 = fmaxf(fmaxf(m0, m1), m2);
            const float t1 = fmaxf(fmaxf(m3, m4), acc[15]);
            const float tv = fmaxf(t0, t1);
            const bool gt = tv > b1;                            // strict >: first tile wins ties
            b2 = fmaxf(b2, gt ? b1 : tv);
            b1 = gt ? tv : b1;
            bt = gt ? (ch * 8 + t) : bt;                        // ascending tile ids 0..127
        }
        __syncthreads();                                        // drains next-chunk loads + read fence
    }

    // epilogue: recompute winning tile's 16 rows (this k-half) in f32; exact within-tile top-2
    bool needy;
    int ei = 0;
    {
        const f16x8* cap = carr + (size_t)(book * 3) * CSZ;
        float v1 = -1e30f, v2 = b2;
#pragma unroll
        for (int r = 0; r < 16; ++r) {
            const int row = (r & 3) + 8 * (r >> 2) + 4 * h;      // ascending per half
            const int ent = bt * 32 + row;
            const f16x8 p0 = cap[ent];
            const f16x8 p1 = cap[CSZ + ent];
            const f16x8 p2 = cap[2 * CSZ + ent];
            float sr = 0.f;
#pragma unroll
            for (int j = 0; j < 8; ++j) {
                sr += (float)p0[j] * (float)s0[j];
                sr += (float)p1[j] * (float)s1[j];
                sr += (float)p2[j] * (float)s2[j];
            }
            const bool gt = sr > v1;
            v2 = fmaxf(v2, gt ? v1 : sr);
            v1 = gt ? sr : v1;
            ei = gt ? ent : ei;
        }
        const float o1 = __shfl_xor(v1, 32);
        const int   oe = __shfl_xor(ei, 32);
        const float o2 = __shfl_xor(v2, 32);
        v2 = fmaxf(fmaxf(v2, o2), fminf(v1, o1));
        const bool tk = (o1 > v1) || (o1 == v1 && oe < ei);
        v1 = tk ? o1 : v1;
        ei = tk ? oe : ei;
        needy = (v1 - v2) < TAU;
    }

    if (lane < 32) { sE[book][fl] = ei; sN[book][fl] = needy ? 1 : 0; }
    __syncthreads();

    if (wave == 0) {
        sCode[lane] = (sE[0][lane] << 12) | sE[1][lane];
        const int flags = sN[0][lane] | (sN[1][lane] << 1);
        const unsigned long long mk = __ballot(flags != 0);
        const int pos = (int)__popcll(mk & ((1ull << lane) - 1));
        if (flags) sList[pos] = lane | (flags << 8);
        if (lane == 0) sCnt = (int)__popcll(mk);
    }
    __syncthreads();

    // inline exact f64 rescue: one wave per needy frame
    {
        const int n = sCnt;
        for (int rr = wave; rr < n; rr += 4) {
            const int item = sList[rr];
            const int fr = item & 63;
            const bool nA = (item >> 8) & 1, nB = (item >> 9) & 1;
            const double* zr = za64 + ((size_t)(bf + fr)) * 16;  // uniform -> s_load
            double zra[16];
#pragma unroll
            for (int k = 0; k < 16; ++k) zra[k] = zr[k];
            double n2a = 0.0, n2b = 0.0;
#pragma unroll
            for (int k = 0; k < 8; ++k) { n2a = fma(zra[k], zra[k], n2a); n2b = fma(zra[8+k], zra[8+k], n2b); }
            const double ja_ = 1.0 / fmax(sqrt(n2a), 1e-12);
            const double jb_ = 1.0 / fmax(sqrt(n2b), 1e-12);

            double bva = -1e300, bvb = -1e300; int ba = 0, bb = 0;
            if (nA) {
                double ea[8];
#pragma unroll
                for (int k = 0; k < 8; ++k) ea[k] = zra[k] * ja_;
                for (int e = lane; e < CSZ; e += 64) {
                    const double* ra = cbn64A + (size_t)e * 8;
                    double sA = 0.0;
#pragma unroll
                    for (int k = 0; k < 8; ++k) sA = fma(ea[k], ra[k], sA);
                    if (sA > bva) { bva = sA; ba = e; }
                }
            }
            if (nB) {
                double eb[8];
#pragma unroll
                for (int k = 0; k < 8; ++k) eb[k] = zra[8 + k] * jb_;
                for (int e = lane; e < CSZ; e += 64) {
                    const double* rb = cbn64B + (size_t)e * 8;
                    double sB = 0.0;
#pragma unroll
                    for (int k = 0; k < 8; ++k) sB = fma(eb[k], rb[k], sB);
                    if (sB > bvb) { bvb = sB; bb = e; }
                }
            }
#pragma unroll
            for (int off = 32; off > 0; off >>= 1) {
                double ov = __shfl_xor(bva, off); int oi = __shfl_xor(ba, off);
                if (ov > bva || (ov == bva && oi < ba)) { bva = ov; ba = oi; }
                ov = __shfl_xor(bvb, off); oi = __shfl_xor(bb, off);
                if (ov > bvb || (ov == bvb && oi < bb)) { bvb = ov; bb = oi; }
            }
            if (lane == 0) {
                const int old = sCode[fr];
                const int ia2 = nA ? ba : (old >> 12);
                const int ib2 = nB ? bb : (old & 4095);
                sCode[fr] = (ia2 << 12) | ib2;
            }
        }
    }
    __syncthreads();

    if (wave == 0) {
        const int code = sCode[lane];
        idxAB[bf + lane] = code;
        out[IDX_OFF + (size_t)(bf + lane)] = (float)code;        // < 2^24: exact in f32
    }
    if (wave == 1) {
        const int code = sCode[lane];
        const int iA = code >> 12, iB = code & 4095;
        const float4 qa0 = *(const float4*)(cb_a + (size_t)iA * CDIM);
        const float4 qa1 = *(const float4*)(cb_a + (size_t)iA * CDIM + 4);
        const float4 qb0 = *(const float4*)(cb_b + (size_t)iB * CDIM);
        const float4 qb1 = *(const float4*)(cb_b + (size_t)iB * CDIM + 4);
        const float zaq[8] = {qa0.x, qa0.y, qa0.z, qa0.w, qa1.x, qa1.y, qa1.z, qa1.w};
        const float zbq[8] = {qb0.x, qb0.y, qb0.z, qb0.w, qb1.x, qb1.y, qb1.z, qb1.w};
        const double* zp = za64 + (size_t)(bf + lane) * 16;
        double s = 0.0;
#pragma unroll
        for (int k = 0; k < 8; ++k) {
            const double d0 = zp[k]     - (double)zaq[k]; s = fma(d0, d0, s);
            const double d1 = zp[8 + k] - (double)zbq[k]; s = fma(d1, d1, s);
        }
#pragma unroll
        for (int off = 32; off > 0; off >>= 1) s += __shfl_down(s, off);  // fixed order
        if (lane == 0) part[blockIdx.x] = s;
    }
}

// ================= C: streaming out-projection; no LDS, 4096 blocks (16/CU) =================
// block = (b, t-quarter, 8-channel group in one book); thread = one t-quad.
// Output is write-once/never-read -> non-temporal stores keep gathers L2-hot.
__global__ void __launch_bounds__(256)
vq_store(const int* __restrict__ idxAB,
         const float* __restrict__ cb_a, const float* __restrict__ cb_b,
         const float* __restrict__ w_out_a, const float* __restrict__ b_out_a,
         const float* __restrict__ w_out_b, const float* __restrict__ b_out_b,
         float* __restrict__ out) {
    const int tid = threadIdx.x;
    const int blk = blockIdx.x;                                  // 4096 = 8 b x 4 tq x 128 cg
    const int b   = blk >> 9;
    const int tq  = (blk >> 7) & 3;
    const int cg  = blk & 127;
    const bool bookb = (cg >= 64);
    const float* cbp = bookb ? cb_b : cb_a;
    const float* wO  = bookb ? w_out_b : w_out_a;
    const float* bO  = bookb ? b_out_b : b_out_a;
    const int cl0 = (cg & 63) << 3;                              // channel base within book

    // weights & biases: block-uniform -> scalar loads
    float wv[8][8];
    float bias[8];
#pragma unroll
    for (int ch = 0; ch < 8; ++ch) {
        const float* wr = wO + (size_t)(cl0 + ch) * 8;
#pragma unroll
        for (int k = 0; k < 8; ++k) wv[ch][k] = wr[k];
        bias[ch] = bO[cl0 + ch];
    }

    const size_t outbase = ((size_t)b * ND + (bookb ? 512 : 0) + cl0) * NT;
    const int t0 = (tq << 10) + (tid << 2);
    const int4 codes = *(const int4*)(idxAB + (b << 12) + t0);   // coalesced 1KB/wave
    const int cd[4] = {codes.x, codes.y, codes.z, codes.w};
    float4 q0[4], q1[4];
#pragma unroll
    for (int j = 0; j < 4; ++j) {
        const int idx = bookb ? (cd[j] & 4095) : (cd[j] >> 12);
        q0[j] = *(const float4*)(cbp + (size_t)idx * CDIM);
        q1[j] = *(const float4*)(cbp + (size_t)idx * CDIM + 4);
    }
#pragma unroll
    for (int ch = 0; ch < 8; ++ch) {
        f32x4 o;
#pragma unroll
        for (int j = 0; j < 4; ++j) {
            float acc = bias[ch];
            acc = fmaf(wv[ch][0], q0[j].x, acc); acc = fmaf(wv[ch][1], q0[j].y, acc);
            acc = fmaf(wv[ch][2], q0[j].z, acc); acc = fmaf(wv[ch][3], q0[j].w, acc);
            acc = fmaf(wv[ch][4], q1[j].x, acc); acc = fmaf(wv[ch][5], q1[j].y, acc);
            acc = fmaf(wv[ch][6], q1[j].z, acc); acc = fmaf(wv[ch][7], q1[j].w, acc);
            o[j] = acc;
        }
        __builtin_nontemporal_store(o, (f32x4*)(out + outbase + (size_t)ch * NT + t0));
    }
}

__global__ void vq_finalize64(const double* __restrict__ part, float* __restrict__ out) {
    const int b = threadIdx.x;
    if (b < NB) {
        double s = 0.0;
        for (int j = 0; j < 64; ++j) s += part[(size_t)b * 64 + j];   // fixed order
        const float v = (float)(s * (1.0 / 32768.0));
        out[CL_OFF + b]  = v;
        out[CBL_OFF + b] = v;
    }
}

// ================= fallback monolith (round-1 proven, if ws too small) =================
__global__ void __launch_bounds__(256, 2)
vq_mono(const float* __restrict__ z,
        const float* __restrict__ w_in_a, const float* __restrict__ b_in_a,
        const float* __restrict__ w_in_b, const float* __restrict__ b_in_b,
        const float* __restrict__ w_out_a, const float* __restrict__ b_out_a,
        const float* __restrict__ w_out_b, const float* __restrict__ b_out_b,
        const float* __restrict__ cb_a, const float* __restrict__ cb_b,
        float* __restrict__ out, double* __restrict__ part) {
    const int tid  = threadIdx.x;
    const int lane = tid & 63;
    const int wave = __builtin_amdgcn_readfirstlane(tid >> 6);
    const int blk  = blockIdx.x;
    const int b    = blk >> 6;
    const int t    = ((blk & 63) << 6) + lane;

    __shared__ double red[4][64][9];
    __shared__ double sBest[2][4][64];
    __shared__ int    sIdx[2][4][64];

    double acc[16];
#pragma unroll
    for (int k = 0; k < 16; ++k) acc[k] = 0.0;
    const float* zp = z + ((size_t)b * ND) * NT + t;
    const int i0 = wave * 256;
#pragma unroll 2
    for (int ii = 0; ii < 256; ++ii) {
        const int i = i0 + ii;
        const double zd = (double)zp[(size_t)i * NT];
#pragma unroll
        for (int o = 0; o < 8; ++o) {
            acc[o]     = fma((double)w_in_a[o * ND + i], zd, acc[o]);
            acc[8 + o] = fma((double)w_in_b[o * ND + i], zd, acc[8 + o]);
        }
    }
    double za[16];
#pragma unroll
    for (int r = 0; r < 2; ++r) {
#pragma unroll
        for (int k = 0; k < 8; ++k) red[wave][lane][k] = acc[8 * r + k];
        __syncthreads();
#pragma unroll
        for (int k = 0; k < 8; ++k)
            za[8*r+k] = ((red[0][lane][k] + red[1][lane][k]) + red[2][lane][k]) + red[3][lane][k];
        __syncthreads();
    }
#pragma unroll
    for (int k = 0; k < 8; ++k) { za[k] += (double)b_in_a[k]; za[8 + k] += (double)b_in_b[k]; }

    if (wave == 0) {
#pragma unroll
        for (int k = 0; k < 16; ++k)
            out[LAT_OFF + ((size_t)b * 16 + k) * NT + t] = (float)za[k];
    }

    double ea[8], eb[8];
    {
        double n2 = 0.0;
#pragma unroll
        for (int k = 0; k < 8; ++k) n2 = fma(za[k], za[k], n2);
        double inv = 1.0 / fmax(sqrt(n2), 1e-12);
#pragma unroll
        for (int k = 0; k < 8; ++k) ea[k] = za[k] * inv;
    }
    {
        double n2 = 0.0;
#pragma unroll
        for (int k = 0; k < 8; ++k) n2 = fma(za[8 + k], za[8 + k], n2);
        double inv = 1.0 / fmax(sqrt(n2), 1e-12);
#pragma unroll
        for (int k = 0; k < 8; ++k) eb[k] = za[8 + k] * inv;
    }

    double bestA = -1e300, bestB = -1e300;
    int ibA = 0, ibB = 0;
    const int j0 = wave << 10;
    for (int jj = 0; jj < 1024; ++jj) {
        const int j = j0 + jj;
        const float* ra = cb_a + (size_t)j * CDIM;
        const float* rb = cb_b + (size_t)j * CDIM;
        double na = 0.0, nb = 0.0, sA = 0.0, sB = 0.0;
#pragma unroll
        for (int k = 0; k < 8; ++k) {
            double av = (double)ra[k], bv2 = (double)rb[k];
            na = fma(av, av, na); nb = fma(bv2, bv2, nb);
            sA = fma(ea[k], av, sA); sB = fma(eb[k], bv2, sB);
        }
        sA /= fmax(sqrt(na), 1e-12);
        sB /= fmax(sqrt(nb), 1e-12);
        if (sA > bestA) { bestA = sA; ibA = j; }
        if (sB > bestB) { bestB = sB; ibB = j; }
    }
    sBest[0][wave][lane] = bestA; sIdx[0][wave][lane] = ibA;
    sBest[1][wave][lane] = bestB; sIdx[1][wave][lane] = ibB;
    __syncthreads();

    double bA = sBest[0][0][lane]; int iA = sIdx[0][0][lane];
    double bB = sBest[1][0][lane]; int iB = sIdx[1][0][lane];
#pragma unroll
    for (int w2 = 1; w2 < 4; ++w2) {
        double d = sBest[0][w2][lane]; int j2 = sIdx[0][w2][lane];
        if (d > bA) { bA = d; iA = j2; }
        d = sBest[1][w2][lane]; j2 = sIdx[1][w2][lane];
        if (d > bB) { bB = d; iB = j2; }
    }

    float4 qa0 = *(const float4*)(cb_a + (size_t)iA * CDIM);
    float4 qa1 = *(const float4*)(cb_a + (size_t)iA * CDIM + 4);
    float4 qb0 = *(const float4*)(cb_b + (size_t)iB * CDIM);
    float4 qb1 = *(const float4*)(cb_b + (size_t)iB * CDIM + 4);
    float zaq[8] = {qa0.x, qa0.y, qa0.z, qa0.w, qa1.x, qa1.y, qa1.z, qa1.w};
    float zbq[8] = {qb0.x, qb0.y, qb0.z, qb0.w, qb1.x, qb1.y, qb1.z, qb1.w};

    if (wave == 0) {
        out[IDX_OFF + (size_t)b * NT + t] = (float)(iA * CSZ + iB);
        double s = 0.0;
#pragma unroll
        for (int k = 0; k < 8; ++k) {
            double d0 = za[k]     - (double)zaq[k]; s = fma(d0, d0, s);
            double d1 = za[8 + k] - (double)zbq[k]; s = fma(d1, d1, s);
        }
#pragma unroll
        for (int off = 32; off > 0; off >>= 1) s += __shfl_down(s, off);
        if (lane == 0) part[blk] = s;
    }

    const int c0 = wave << 7;
    const size_t obase = ((size_t)b * ND) * NT + t;
    for (int cc = 0; cc < 128; ++cc) {
        const int c = c0 + cc;
        const float* wa = w_out_a + (size_t)c * CDIM;
        const float* wb = w_out_b + (size_t)c * CDIM;
        float sa = b_out_a[c], sb = b_out_b[c];
#pragma unroll
        for (int k = 0; k < 8; ++k) { sa = fmaf(wa[k], zaq[k], sa); sb = fmaf(wb[k], zbq[k], sb); }
        out[obase + (size_t)c * NT]         = sa;
        out[obase + (size_t)(512 + c) * NT] = sb;
    }
}

extern "C" void kernel_launch(void* const* d_in, const int* in_sizes, int n_in,
                              void* d_out, int out_size, void* d_ws, size_t ws_size,
                              hipStream_t stream) {
    const float* z       = (const float*)d_in[0];
    const float* w_in_a  = (const float*)d_in[1];
    const float* b_in_a  = (const float*)d_in[2];
    const float* w_in_b  = (const float*)d_in[3];
    const float* b_in_b  = (const float*)d_in[4];
    const float* w_out_a = (const float*)d_in[5];
    const float* b_out_a = (const float*)d_in[6];
    const float* w_out_b = (const float*)d_in[7];
    const float* b_out_b = (const float*)d_in[8];
    const float* cb_a    = (const float*)d_in[9];
    const float* cb_b    = (const float*)d_in[10];
    float* out = (float*)d_out;
    char* ws = (char*)d_ws;

    if (ws_size >= WS_NEED) {
        double* wT64   = (double*)(ws + WT64_B);
        double* cbn64A = (double*)(ws + CBN64A_B);
        double* cbn64B = (double*)(ws + CBN64B_B);
        f16x8*  carr   = (f16x8*) (ws + CARR_B);
        double* za64   = (double*)(ws + ZA64_B);
        int*    idxAB  = (int*)   (ws + IDXW_B);
        f16x8*  earr   = (f16x8*) (ws + EARR_B);
        double* part   = (double*)(ws + PART_B);

        vq_prep<<<96, 256, 0, stream>>>(w_in_a, w_in_b, cb_a, cb_b,
                                        wT64, cbn64A, cbn64B, carr);
        vq_proj<<<512, 512, 0, stream>>>(z, b_in_a, b_in_b, wT64, za64, earr, out);
        vq_scan32<<<512, 256, 0, stream>>>(carr, earr, za64, cbn64A, cbn64B,
                                           cb_a, cb_b, idxAB, out, part);
        vq_store<<<4096, 256, 0, stream>>>(idxAB, cb_a, cb_b,
                                           w_out_a, b_out_a, w_out_b, b_out_b, out);
        vq_finalize64<<<1, 64, 0, stream>>>(part, out);
    } else {
        double* part = (double*)ws;
        vq_mono<<<512, 256, 0, stream>>>(z, w_in_a, b_in_a, w_in_b, b_in_b,
                                         w_out_a, b_out_a, w_out_b, b_out_b,
                                         cb_a, cb_b, out, part);
        vq_finalize64<<<1, 64, 0, stream>>>(part, out);
    }
}

// Round 16
// 128.288 us; speedup vs baseline: 1.0519x; 1.0519x over previous
//
#include <hip/hip_runtime.h>
#include <math.h>

#define CDIM 8
#define CSZ  4096
#define NB   8
#define ND   1024
#define NT   4096
#define NFR  (NB * NT)
#define TAU  2e-5f                   // f16-split-MFMA vs f64 sim gap (worst-stack ~5e-6, 4x margin)

typedef float    f32x4  __attribute__((ext_vector_type(4)));
typedef float    f32x16 __attribute__((ext_vector_type(16)));
typedef _Float16 f16x8  __attribute__((ext_vector_type(8)));

// async global->LDS, 16B per lane; dest must be linear-in-lane (ours is)
#define GLOAD_LDS16(gp, lp) __builtin_amdgcn_global_load_lds( \
    (const __attribute__((address_space(1))) void*)(gp), \
    (__attribute__((address_space(3))) void*)(lp), 16, 0, 0)

// ---- d_out layout (flat f32, return order) ----
static constexpr size_t CL_OFF  = (size_t)NB * ND * NT;
static constexpr size_t CBL_OFF = CL_OFF + NB;
static constexpr size_t IDX_OFF = CBL_OFF + NB;
static constexpr size_t LAT_OFF = IDX_OFF + (size_t)NB * NT;

// ---- d_ws layout (byte offsets, 16B aligned) ----
static constexpr size_t WT64_B   = 0;                          // f64[16384]
static constexpr size_t CBN64A_B = 131072;                     // f64[4096*8]
static constexpr size_t CBN64B_B = 393216;                     // f64[4096*8]
static constexpr size_t CARR_B   = 655360;                     // f16x8 [book*3+plane][4096] = 384 KB
static constexpr size_t ZA64_B   = 1048576;                    // f64[NFR*16] = 4 MB
static constexpr size_t IDXW_B   = 5242880;                    // i32[NFR]
static constexpr size_t EARR_B   = 5373952;                    // f16x8 [frame][book*3+slot] = 3 MB
static constexpr size_t PART_B   = 8519680;                    // f64[512]
static constexpr size_t WS_NEED  = PART_B + 512 * 8;           // ~8.52 MB

// split x: hi (f16) + lo*64 (f16) + hi/64 (f16); |x|<2^-10 routed all-lo (no denorm loss).
// sim = chi*ehi + (chi/64)*(elo*64) + (clo*64)*(ehi/64)
__device__ __forceinline__ void split16(float x, _Float16& hi, _Float16& lo64, _Float16& hi64) {
    const _Float16 h = (fabsf(x) < 0.0009765625f) ? (_Float16)0.f : (_Float16)x;
    const float hf = (float)h;
    hi   = h;
    lo64 = (_Float16)((x - hf) * 64.f);
    hi64 = (_Float16)(hf * 0.015625f);
}

// ================= prep: wT64 + f64-normalized codebooks + f16-split planes =================
__global__ void vq_prep(const float* __restrict__ w_in_a, const float* __restrict__ w_in_b,
                        const float* __restrict__ cb_a,  const float* __restrict__ cb_b,
                        double* __restrict__ wT64,
                        double* __restrict__ cbn64A, double* __restrict__ cbn64B,
                        f16x8* __restrict__ carr) {
    int id = blockIdx.x * 256 + threadIdx.x;
    if (id < 16384) {
        int i = id >> 4, o = id & 15;
        float w = (o < 8) ? w_in_a[o * ND + i] : w_in_b[(o - 8) * ND + i];
        wT64[id] = (double)w;
    } else if (id < 16384 + 2 * CSZ) {
        int e = id - 16384;
        int book = e >> 12, j = e & (CSZ - 1);
        const float* src = (book ? cb_b : cb_a) + (size_t)j * CDIM;
        double* d64 = (book ? cbn64B : cbn64A) + (size_t)j * CDIM;
        double c[CDIM]; double n2 = 0.0;
#pragma unroll
        for (int k = 0; k < CDIM; ++k) { c[k] = (double)src[k]; n2 = fma(c[k], c[k], n2); }
        double den = fmax(sqrt(n2), 1e-12);
        f16x8 p0, p1, p2;
#pragma unroll
        for (int k = 0; k < CDIM; ++k) {
            double v = c[k] / den;
            d64[k] = v;
            _Float16 hi, lo64, hi64;
            split16((float)v, hi, lo64, hi64);
            p0[k] = hi; p1[k] = hi64; p2[k] = lo64;   // plane1 = chi/64, plane2 = clo*64
        }
        const size_t base = (size_t)(book * 3) * CSZ + j;
        carr[base]           = p0;
        carr[base + CSZ]     = p1;
        carr[base + 2 * CSZ] = p2;
    }
}

// ================= A: f64 projection (proven 512x512 shape) =================
__global__ void __launch_bounds__(512, 4)
vq_proj(const float* __restrict__ z,
        const float* __restrict__ b_in_a, const float* __restrict__ b_in_b,
        const double* __restrict__ wT64,
        double* __restrict__ za64, f16x8* __restrict__ earr,
        float* __restrict__ out) {
    const int tid  = threadIdx.x;
    const int lane = tid & 63;
    const int wave = __builtin_amdgcn_readfirstlane(tid >> 6);  // 0..7
    const int blk  = blockIdx.x;
    const int b    = blk >> 6;
    const int t    = ((blk & 63) << 6) + lane;
    const int f    = (blk << 6) + lane;

    __shared__ double red[8][64][9];                            // 36.9 KB

    double acc[16];
#pragma unroll
    for (int k = 0; k < 16; ++k) acc[k] = 0.0;

    const float* zp = z + ((size_t)b * ND) * NT + t;
    const int i0 = wave * 128;
#pragma unroll 4
    for (int ii = 0; ii < 128; ++ii) {
        const int i = i0 + ii;
        const double zd = (double)zp[(size_t)i * NT];
        const double* wr = wT64 + (size_t)i * 16;               // uniform -> s_load
#pragma unroll
        for (int k = 0; k < 16; ++k) acc[k] = fma(wr[k], zd, acc[k]);
    }

    double za16[16];
#pragma unroll
    for (int r = 0; r < 2; ++r) {
#pragma unroll
        for (int k = 0; k < 8; ++k) red[wave][lane][k] = acc[8 * r + k];
        __syncthreads();
        if (wave == 0) {
#pragma unroll
            for (int k = 0; k < 8; ++k) {
                double s = red[0][lane][k];
#pragma unroll
                for (int w = 1; w < 8; ++w) s += red[w][lane][k];
                za16[8 * r + k] = s;
            }
        }
        __syncthreads();
    }
    if (wave != 0) return;

#pragma unroll
    for (int k = 0; k < 8; ++k) { za16[k] += (double)b_in_a[k]; za16[8 + k] += (double)b_in_b[k]; }

    // latent output (f32)
#pragma unroll
    for (int k = 0; k < 16; ++k)
        out[LAT_OFF + ((size_t)b * 16 + k) * NT + t] = (float)za16[k];

    // store za64 (rescue + losses)
    double* zf = za64 + (size_t)f * 16;
#pragma unroll
    for (int k = 0; k < 16; ++k) zf[k] = za16[k];

    // normalize f64 -> f16-split slots [f][book*3 + {ehi, elo*64, ehi/64}]
    double n2a = 0.0, n2b = 0.0;
#pragma unroll
    for (int k = 0; k < 8; ++k) { n2a = fma(za16[k], za16[k], n2a); n2b = fma(za16[8+k], za16[8+k], n2b); }
    const double ia_ = 1.0 / fmax(sqrt(n2a), 1e-12);
    const double ib_ = 1.0 / fmax(sqrt(n2b), 1e-12);
#pragma unroll
    for (int book = 0; book < 2; ++book) {
        const double inv = book ? ib_ : ia_;
        f16x8 s0, s1, s2;
#pragma unroll
        for (int k = 0; k < 8; ++k) {
            const float e32 = (float)(za16[book * 8 + k] * inv);
            _Float16 hi, lo64, hi64;
            split16(e32, hi, lo64, hi64);
            s0[k] = hi; s1[k] = lo64; s2[k] = hi64;
        }
        const size_t base = (size_t)f * 6 + book * 3;
        earr[base]     = s0;
        earr[base + 1] = s1;
        earr[base + 2] = s2;
    }
}

// ================= B: MFMA scan + inline rescue + idx out + loss; 512 blocks x 256 =================
__global__ void __launch_bounds__(256, 2)
vq_scan32(const f16x8* __restrict__ carr, const f16x8* __restrict__ earr,
          const double* __restrict__ za64,
          const double* __restrict__ cbn64A, const double* __restrict__ cbn64B,
          const float* __restrict__ cb_a, const float* __restrict__ cb_b,
          int* __restrict__ idxAB, float* __restrict__ out, double* __restrict__ part) {
    __shared__ f16x8 lds[6 * 512];                              // 48 KB
    __shared__ int sE[2][64], sN[2][64], sCode[64], sList[64];
    __shared__ int sCnt;

    const int tid  = threadIdx.x;
    const int lane = tid & 63;
    const int wave = __builtin_amdgcn_readfirstlane(tid >> 6);  // 0..3
    const int book = wave & 1;
    const int fg   = wave >> 1;
    const int h    = lane >> 5;                                 // k-half
    const int c32  = lane & 31;
    const int fl   = fg * 32 + c32;
    const int bf   = blockIdx.x * 64;
    const int f    = bf + fl;

    const f16x8 s0 = earr[(size_t)f * 6 + book * 3];
    const f16x8 s1 = earr[(size_t)f * 6 + book * 3 + 1];
    const f16x8 s2 = earr[(size_t)f * 6 + book * 3 + 2];
    f16x8 fz;
#pragma unroll
    for (int j = 0; j < 8; ++j) fz[j] = (_Float16)0.f;
    const f16x8 bf1 = h ? s1 : s0;
    const f16x8 bf2 = h ? fz : s2;

    float b1 = -1e30f, b2 = -1e30f;
    int   bt = 0;

    for (int ch = 0; ch < 8; ++ch) {
        __syncthreads();
#pragma unroll
        for (int it = 0; it < 12; ++it) {                       // async stage 3072 f16x8 = 48 KB
            const int idx = it * 256 + tid;
            const int pp = idx >> 9, e = idx & 511;
            GLOAD_LDS16(carr + (size_t)pp * CSZ + (ch << 9) + e, lds + idx);
        }
        __syncthreads();                                        // vmcnt(0) drain before reads
        const f16x8* pa1 = lds + (book * 3 + h) * 512;
        const f16x8* pa2 = lds + (book * 3 + 2) * 512;
#pragma unroll 4
        for (int t = 0; t < 16; ++t) {
            const f16x8 af1 = pa1[(t << 5) + c32];
            const f16x8 af2 = pa2[(t << 5) + c32];
            f32x16 zc = {};
            f32x16 acc = __builtin_amdgcn_mfma_f32_32x32x16_f16(af1, bf1, zc, 0, 0, 0);
            acc = __builtin_amdgcn_mfma_f32_32x32x16_f16(af2, bf2, acc, 0, 0, 0);
            // max3-shaped tree (max is exactly associative: identical value, fewer insts)
            const float m0 = fmaxf(fmaxf(acc[0],  acc[1]),  acc[2]);
            const float m1 = fmaxf(fmaxf(acc[3],  acc[4]),  acc[5]);
            const float m2 = fmaxf(fmaxf(acc[6],  acc[7]),  acc[8]);
            const float m3 = fmaxf(fmaxf(acc[9],  acc[10]), acc[11]);
            const float m4 = fmaxf(fmaxf(acc[12], acc[13]), acc[14]);
            const float t0 = fmaxf(fmaxf(m0, m1), m2);
            const float t1 = fmaxf(fmaxf(m3, m4), acc[15]);
            const float tv = fmaxf(t0, t1);
            const bool gt = tv > b1;                            // strict >: first tile wins ties
            b2 = fmaxf(b2, gt ? b1 : tv);
            b1 = gt ? tv : b1;
            bt = gt ? (ch * 16 + t) : bt;
        }
    }

    // epilogue: recompute winning tile's 16 rows (this k-half) in f32; exact within-tile top-2
    bool needy;
    int ei = 0;
    {
        const f16x8* cap = carr + (size_t)(book * 3) * CSZ;
        float v1 = -1e30f, v2 = b2;
#pragma unroll
        for (int r = 0; r < 16; ++r) {
            const int row = (r & 3) + 8 * (r >> 2) + 4 * h;      // ascending per half
            const int ent = bt * 32 + row;
            const f16x8 p0 = cap[ent];
            const f16x8 p1 = cap[CSZ + ent];
            const f16x8 p2 = cap[2 * CSZ + ent];
            float sr = 0.f;
#pragma unroll
            for (int j = 0; j < 8; ++j) {
                sr += (float)p0[j] * (float)s0[j];
                sr += (float)p1[j] * (float)s1[j];
                sr += (float)p2[j] * (float)s2[j];
            }
            const bool gt = sr > v1;
            v2 = fmaxf(v2, gt ? v1 : sr);
            v1 = gt ? sr : v1;
            ei = gt ? ent : ei;
        }
        const float o1 = __shfl_xor(v1, 32);
        const int   oe = __shfl_xor(ei, 32);
        const float o2 = __shfl_xor(v2, 32);
        v2 = fmaxf(fmaxf(v2, o2), fminf(v1, o1));
        const bool tk = (o1 > v1) || (o1 == v1 && oe < ei);
        v1 = tk ? o1 : v1;
        ei = tk ? oe : ei;
        needy = (v1 - v2) < TAU;
    }

    if (lane < 32) { sE[book][fl] = ei; sN[book][fl] = needy ? 1 : 0; }
    __syncthreads();

    if (wave == 0) {
        sCode[lane] = (sE[0][lane] << 12) | sE[1][lane];
        const int flags = sN[0][lane] | (sN[1][lane] << 1);
        const unsigned long long mk = __ballot(flags != 0);
        const int pos = (int)__popcll(mk & ((1ull << lane) - 1));
        if (flags) sList[pos] = lane | (flags << 8);
        if (lane == 0) sCnt = (int)__popcll(mk);
    }
    __syncthreads();

    // inline exact f64 rescue: one wave per needy frame
    {
        const int n = sCnt;
        for (int rr = wave; rr < n; rr += 4) {
            const int item = sList[rr];
            const int fr = item & 63;
            const bool nA = (item >> 8) & 1, nB = (item >> 9) & 1;
            const double* zr = za64 + ((size_t)(bf + fr)) * 16;  // uniform -> s_load
            double zra[16];
#pragma unroll
            for (int k = 0; k < 16; ++k) zra[k] = zr[k];
            double n2a = 0.0, n2b = 0.0;
#pragma unroll
            for (int k = 0; k < 8; ++k) { n2a = fma(zra[k], zra[k], n2a); n2b = fma(zra[8+k], zra[8+k], n2b); }
            const double ja_ = 1.0 / fmax(sqrt(n2a), 1e-12);
            const double jb_ = 1.0 / fmax(sqrt(n2b), 1e-12);

            double bva = -1e300, bvb = -1e300; int ba = 0, bb = 0;
            if (nA) {
                double ea[8];
#pragma unroll
                for (int k = 0; k < 8; ++k) ea[k] = zra[k] * ja_;
                for (int e = lane; e < CSZ; e += 64) {
                    const double* ra = cbn64A + (size_t)e * 8;
                    double sA = 0.0;
#pragma unroll
                    for (int k = 0; k < 8; ++k) sA = fma(ea[k], ra[k], sA);
                    if (sA > bva) { bva = sA; ba = e; }
                }
            }
            if (nB) {
                double eb[8];
#pragma unroll
                for (int k = 0; k < 8; ++k) eb[k] = zra[8 + k] * jb_;
                for (int e = lane; e < CSZ; e += 64) {
                    const double* rb = cbn64B + (size_t)e * 8;
                    double sB = 0.0;
#pragma unroll
                    for (int k = 0; k < 8; ++k) sB = fma(eb[k], rb[k], sB);
                    if (sB > bvb) { bvb = sB; bb = e; }
                }
            }
#pragma unroll
            for (int off = 32; off > 0; off >>= 1) {
                double ov = __shfl_xor(bva, off); int oi = __shfl_xor(ba, off);
                if (ov > bva || (ov == bva && oi < ba)) { bva = ov; ba = oi; }
                ov = __shfl_xor(bvb, off); oi = __shfl_xor(bb, off);
                if (ov > bvb || (ov == bvb && oi < bb)) { bvb = ov; bb = oi; }
            }
            if (lane == 0) {
                const int old = sCode[fr];
                const int ia2 = nA ? ba : (old >> 12);
                const int ib2 = nB ? bb : (old & 4095);
                sCode[fr] = (ia2 << 12) | ib2;
            }
        }
    }
    __syncthreads();

    if (wave == 0) {
        const int code = sCode[lane];
        idxAB[bf + lane] = code;
        out[IDX_OFF + (size_t)(bf + lane)] = (float)code;        // < 2^24: exact in f32
    }
    if (wave == 1) {
        const int code = sCode[lane];
        const int iA = code >> 12, iB = code & 4095;
        const float4 qa0 = *(const float4*)(cb_a + (size_t)iA * CDIM);
        const float4 qa1 = *(const float4*)(cb_a + (size_t)iA * CDIM + 4);
        const float4 qb0 = *(const float4*)(cb_b + (size_t)iB * CDIM);
        const float4 qb1 = *(const float4*)(cb_b + (size_t)iB * CDIM + 4);
        const float zaq[8] = {qa0.x, qa0.y, qa0.z, qa0.w, qa1.x, qa1.y, qa1.z, qa1.w};
        const float zbq[8] = {qb0.x, qb0.y, qb0.z, qb0.w, qb1.x, qb1.y, qb1.z, qb1.w};
        const double* zp = za64 + (size_t)(bf + lane) * 16;
        double s = 0.0;
#pragma unroll
        for (int k = 0; k < 8; ++k) {
            const double d0 = zp[k]     - (double)zaq[k]; s = fma(d0, d0, s);
            const double d1 = zp[8 + k] - (double)zbq[k]; s = fma(d1, d1, s);
        }
#pragma unroll
        for (int off = 32; off > 0; off >>= 1) s += __shfl_down(s, off);  // fixed order
        if (lane == 0) part[blockIdx.x] = s;
    }
}

// ================= C: streaming out-projection; no LDS, 4096 blocks (16/CU) =================
// block = (b, t-quarter, 8-channel group in one book); thread = one t-quad.
// Output is write-once/never-read -> non-temporal stores keep gathers L2-hot.
__global__ void __launch_bounds__(256)
vq_store(const int* __restrict__ idxAB,
         const float* __restrict__ cb_a, const float* __restrict__ cb_b,
         const float* __restrict__ w_out_a, const float* __restrict__ b_out_a,
         const float* __restrict__ w_out_b, const float* __restrict__ b_out_b,
         float* __restrict__ out) {
    const int tid = threadIdx.x;
    const int blk = blockIdx.x;                                  // 4096 = 8 b x 4 tq x 128 cg
    const int b   = blk >> 9;
    const int tq  = (blk >> 7) & 3;
    const int cg  = blk & 127;
    const bool bookb = (cg >= 64);
    const float* cbp = bookb ? cb_b : cb_a;
    const float* wO  = bookb ? w_out_b : w_out_a;
    const float* bO  = bookb ? b_out_b : b_out_a;
    const int cl0 = (cg & 63) << 3;                              // channel base within book

    // weights & biases: block-uniform -> scalar loads
    float wv[8][8];
    float bias[8];
#pragma unroll
    for (int ch = 0; ch < 8; ++ch) {
        const float* wr = wO + (size_t)(cl0 + ch) * 8;
#pragma unroll
        for (int k = 0; k < 8; ++k) wv[ch][k] = wr[k];
        bias[ch] = bO[cl0 + ch];
    }

    const size_t outbase = ((size_t)b * ND + (bookb ? 512 : 0) + cl0) * NT;
    const int t0 = (tq << 10) + (tid << 2);
    const int4 codes = *(const int4*)(idxAB + (b << 12) + t0);   // coalesced 1KB/wave
    const int cd[4] = {codes.x, codes.y, codes.z, codes.w};
    float4 q0[4], q1[4];
#pragma unroll
    for (int j = 0; j < 4; ++j) {
        const int idx = bookb ? (cd[j] & 4095) : (cd[j] >> 12);
        q0[j] = *(const float4*)(cbp + (size_t)idx * CDIM);
        q1[j] = *(const float4*)(cbp + (size_t)idx * CDIM + 4);
    }
#pragma unroll
    for (int ch = 0; ch < 8; ++ch) {
        f32x4 o;
#pragma unroll
        for (int j = 0; j < 4; ++j) {
            float acc = bias[ch];
            acc = fmaf(wv[ch][0], q0[j].x, acc); acc = fmaf(wv[ch][1], q0[j].y, acc);
            acc = fmaf(wv[ch][2], q0[j].z, acc); acc = fmaf(wv[ch][3], q0[j].w, acc);
            acc = fmaf(wv[ch][4], q1[j].x, acc); acc = fmaf(wv[ch][5], q1[j].y, acc);
            acc = fmaf(wv[ch][6], q1[j].z, acc); acc = fmaf(wv[ch][7], q1[j].w, acc);
            o[j] = acc;
        }
        __builtin_nontemporal_store(o, (f32x4*)(out + outbase + (size_t)ch * NT + t0));
    }
}

__global__ void vq_finalize64(const double* __restrict__ part, float* __restrict__ out) {
    const int b = threadIdx.x;
    if (b < NB) {
        double s = 0.0;
        for (int j = 0; j < 64; ++j) s += part[(size_t)b * 64 + j];   // fixed order
        const float v = (float)(s * (1.0 / 32768.0));
        out[CL_OFF + b]  = v;
        out[CBL_OFF + b] = v;
    }
}

// ================= fallback monolith (round-1 proven, if ws too small) =================
__global__ void __launch_bounds__(256, 2)
vq_mono(const float* __restrict__ z,
        const float* __restrict__ w_in_a, const float* __restrict__ b_in_a,
        const float* __restrict__ w_in_b, const float* __restrict__ b_in_b,
        const float* __restrict__ w_out_a, const float* __restrict__ b_out_a,
        const float* __restrict__ w_out_b, const float* __restrict__ b_out_b,
        const float* __restrict__ cb_a, const float* __restrict__ cb_b,
        float* __restrict__ out, double* __restrict__ part) {
    const int tid  = threadIdx.x;
    const int lane = tid & 63;
    const int wave = __builtin_amdgcn_readfirstlane(tid >> 6);
    const int blk  = blockIdx.x;
    const int b    = blk >> 6;
    const int t    = ((blk & 63) << 6) + lane;

    __shared__ double red[4][64][9];
    __shared__ double sBest[2][4][64];
    __shared__ int    sIdx[2][4][64];

    double acc[16];
#pragma unroll
    for (int k = 0; k < 16; ++k) acc[k] = 0.0;
    const float* zp = z + ((size_t)b * ND) * NT + t;
    const int i0 = wave * 256;
#pragma unroll 2
    for (int ii = 0; ii < 256; ++ii) {
        const int i = i0 + ii;
        const double zd = (double)zp[(size_t)i * NT];
#pragma unroll
        for (int o = 0; o < 8; ++o) {
            acc[o]     = fma((double)w_in_a[o * ND + i], zd, acc[o]);
            acc[8 + o] = fma((double)w_in_b[o * ND + i], zd, acc[8 + o]);
        }
    }
    double za[16];
#pragma unroll
    for (int r = 0; r < 2; ++r) {
#pragma unroll
        for (int k = 0; k < 8; ++k) red[wave][lane][k] = acc[8 * r + k];
        __syncthreads();
#pragma unroll
        for (int k = 0; k < 8; ++k)
            za[8*r+k] = ((red[0][lane][k] + red[1][lane][k]) + red[2][lane][k]) + red[3][lane][k];
        __syncthreads();
    }
#pragma unroll
    for (int k = 0; k < 8; ++k) { za[k] += (double)b_in_a[k]; za[8 + k] += (double)b_in_b[k]; }

    if (wave == 0) {
#pragma unroll
        for (int k = 0; k < 16; ++k)
            out[LAT_OFF + ((size_t)b * 16 + k) * NT + t] = (float)za[k];
    }

    double ea[8], eb[8];
    {
        double n2 = 0.0;
#pragma unroll
        for (int k = 0; k < 8; ++k) n2 = fma(za[k], za[k], n2);
        double inv = 1.0 / fmax(sqrt(n2), 1e-12);
#pragma unroll
        for (int k = 0; k < 8; ++k) ea[k] = za[k] * inv;
    }
    {
        double n2 = 0.0;
#pragma unroll
        for (int k = 0; k < 8; ++k) n2 = fma(za[8 + k], za[8 + k], n2);
        double inv = 1.0 / fmax(sqrt(n2), 1e-12);
#pragma unroll
        for (int k = 0; k < 8; ++k) eb[k] = za[8 + k] * inv;
    }

    double bestA = -1e300, bestB = -1e300;
    int ibA = 0, ibB = 0;
    const int j0 = wave << 10;
    for (int jj = 0; jj < 1024; ++jj) {
        const int j = j0 + jj;
        const float* ra = cb_a + (size_t)j * CDIM;
        const float* rb = cb_b + (size_t)j * CDIM;
        double na = 0.0, nb = 0.0, sA = 0.0, sB = 0.0;
#pragma unroll
        for (int k = 0; k < 8; ++k) {
            double av = (double)ra[k], bv2 = (double)rb[k];
            na = fma(av, av, na); nb = fma(bv2, bv2, nb);
            sA = fma(ea[k], av, sA); sB = fma(eb[k], bv2, sB);
        }
        sA /= fmax(sqrt(na), 1e-12);
        sB /= fmax(sqrt(nb), 1e-12);
        if (sA > bestA) { bestA = sA; ibA = j; }
        if (sB > bestB) { bestB = sB; ibB = j; }
    }
    sBest[0][wave][lane] = bestA; sIdx[0][wave][lane] = ibA;
    sBest[1][wave][lane] = bestB; sIdx[1][wave][lane] = ibB;
    __syncthreads();

    double bA = sBest[0][0][lane]; int iA = sIdx[0][0][lane];
    double bB = sBest[1][0][lane]; int iB = sIdx[1][0][lane];
#pragma unroll
    for (int w2 = 1; w2 < 4; ++w2) {
        double d = sBest[0][w2][lane]; int j2 = sIdx[0][w2][lane];
        if (d > bA) { bA = d; iA = j2; }
        d = sBest[1][w2][lane]; j2 = sIdx[1][w2][lane];
        if (d > bB) { bB = d; iB = j2; }
    }

    float4 qa0 = *(const float4*)(cb_a + (size_t)iA * CDIM);
    float4 qa1 = *(const float4*)(cb_a + (size_t)iA * CDIM + 4);
    float4 qb0 = *(const float4*)(cb_b + (size_t)iB * CDIM);
    float4 qb1 = *(const float4*)(cb_b + (size_t)iB * CDIM + 4);
    float zaq[8] = {qa0.x, qa0.y, qa0.z, qa0.w, qa1.x, qa1.y, qa1.z, qa1.w};
    float zbq[8] = {qb0.x, qb0.y, qb0.z, qb0.w, qb1.x, qb1.y, qb1.z, qb1.w};

    if (wave == 0) {
        out[IDX_OFF + (size_t)b * NT + t] = (float)(iA * CSZ + iB);
        double s = 0.0;
#pragma unroll
        for (int k = 0; k < 8; ++k) {
            double d0 = za[k]     - (double)zaq[k]; s = fma(d0, d0, s);
            double d1 = za[8 + k] - (double)zbq[k]; s = fma(d1, d1, s);
        }
#pragma unroll
        for (int off = 32; off > 0; off >>= 1) s += __shfl_down(s, off);
        if (lane == 0) part[blk] = s;
    }

    const int c0 = wave << 7;
    const size_t obase = ((size_t)b * ND) * NT + t;
    for (int cc = 0; cc < 128; ++cc) {
        const int c = c0 + cc;
        const float* wa = w_out_a + (size_t)c * CDIM;
        const float* wb = w_out_b + (size_t)c * CDIM;
        float sa = b_out_a[c], sb = b_out_b[c];
#pragma unroll
        for (int k = 0; k < 8; ++k) { sa = fmaf(wa[k], zaq[k], sa); sb = fmaf(wb[k], zbq[k], sb); }
        out[obase + (size_t)c * NT]         = sa;
        out[obase + (size_t)(512 + c) * NT] = sb;
    }
}

extern "C" void kernel_launch(void* const* d_in, const int* in_sizes, int n_in,
                              void* d_out, int out_size, void* d_ws, size_t ws_size,
                              hipStream_t stream) {
    const float* z       = (const float*)d_in[0];
    const float* w_in_a  = (const float*)d_in[1];
    const float* b_in_a  = (const float*)d_in[2];
    const float* w_in_b  = (const float*)d_in[3];
    const float* b_in_b  = (const float*)d_in[4];
    const float* w_out_a = (const float*)d_in[5];
    const float* b_out_a = (const float*)d_in[6];
    const float* w_out_b = (const float*)d_in[7];
    const float* b_out_b = (const float*)d_in[8];
    const float* cb_a    = (const float*)d_in[9];
    const float* cb_b    = (const float*)d_in[10];
    float* out = (float*)d_out;
    char* ws = (char*)d_ws;

    if (ws_size >= WS_NEED) {
        double* wT64   = (double*)(ws + WT64_B);
        double* cbn64A = (double*)(ws + CBN64A_B);
        double* cbn64B = (double*)(ws + CBN64B_B);
        f16x8*  carr   = (f16x8*) (ws + CARR_B);
        double* za64   = (double*)(ws + ZA64_B);
        int*    idxAB  = (int*)   (ws + IDXW_B);
        f16x8*  earr   = (f16x8*) (ws + EARR_B);
        double* part   = (double*)(ws + PART_B);

        vq_prep<<<96, 256, 0, stream>>>(w_in_a, w_in_b, cb_a, cb_b,
                                        wT64, cbn64A, cbn64B, carr);
        vq_proj<<<512, 512, 0, stream>>>(z, b_in_a, b_in_b, wT64, za64, earr, out);
        vq_scan32<<<512, 256, 0, stream>>>(carr, earr, za64, cbn64A, cbn64B,
                                           cb_a, cb_b, idxAB, out, part);
        vq_store<<<4096, 256, 0, stream>>>(idxAB, cb_a, cb_b,
                                           w_out_a, b_out_a, w_out_b, b_out_b, out);
        vq_finalize64<<<1, 64, 0, stream>>>(part, out);
    } else {
        double* part = (double*)ws;
        vq_mono<<<512, 256, 0, stream>>>(z, w_in_a, b_in_a, w_in_b, b_in_b,
                                         w_out_a, b_out_a, w_out_b, b_out_b,
                                         cb_a, cb_b, out, part);
        vq_finalize64<<<1, 64, 0, stream>>>(part, out);
    }
}